// Round 1
// baseline (81.606 us; speedup 1.0000x reference)
//
#include <hip/hip_runtime.h>
#include <hip/hip_bf16.h>

#define N_NODES 50000
#define N_EDGES 1600000
#define D_IN    128
#define D_HID   256
#define MAXM    2048

// ws layout (in ints):
//  [0] = int64 flag for edge_index, [1] = bf16 flag for float tensors
//  [16] = match_count
//  [32 .. 32+MAXM] = cnt[MAXM+1]        (deg counts: entry 0 = agent, j+1 = match j)
//  [4096 .. 4096+MAXM-1] = match_src[MAXM]
#define OFF_FLAG 0
#define OFF_MC   16
#define OFF_CNT  32
#define OFF_MSRC 4096

__device__ __forceinline__ float ldf(const void* p, long long i, bool b16) {
    if (b16) {
        unsigned short u = ((const unsigned short*)p)[i];
        unsigned int x = ((unsigned int)u) << 16;
        return __uint_as_float(x);
    }
    return ((const float*)p)[i];
}

__global__ void k_init(const void* edges, const void* state, int* wsi) {
    int tid = threadIdx.x;
    if (tid == 0) {
        // int64 detection: view buffer as 32-bit words; if int64 little-endian,
        // odd words are high halves of values < 2^31 -> all zero.
        const unsigned int* w = (const unsigned int*)edges;
        int i64 = 1;
        for (int k = 1; k < 128; k += 2) {
            if (w[k] != 0u) { i64 = 0; break; }
        }
        wsi[OFF_FLAG] = i64;
        // bf16 detection on state (values ~ N(0,1)): every 16-bit word must look
        // like a plausible bf16 (exp field in a sane range or exactly 0). For f32
        // data the low-mantissa words are ~uniform and fail with P ~ 0.2 each.
        const unsigned short* s = (const unsigned short*)state;
        int b16 = 1;
        for (int k = 0; k < 64; k++) {
            unsigned short v = s[k];
            int e = (v >> 7) & 0xff;
            if (!(v == 0 || (e >= 90 && e <= 140))) { b16 = 0; break; }
        }
        wsi[OFF_FLAG + 1] = b16;
        wsi[OFF_MC] = 0;
    }
    for (int i = tid; i < MAXM + 1; i += blockDim.x) wsi[OFF_CNT + i] = 0;
}

// Pass 1: find edges with dst == agent, record their src.
__global__ void k_scan(const void* edges, const int* agent_p, int* wsi) {
    int agent = agent_p[0];
    int i64 = wsi[OFF_FLAG];
    long long idx0 = (long long)blockIdx.x * blockDim.x + threadIdx.x;
    long long stride = (long long)gridDim.x * blockDim.x;
    if (i64) {
        const long long* src = (const long long*)edges;
        const long long* dst = src + N_EDGES;
        for (long long e = idx0; e < N_EDGES; e += stride) {
            if ((int)dst[e] == agent) {
                int p = atomicAdd(&wsi[OFF_MC], 1);
                if (p < MAXM) wsi[OFF_MSRC + p] = (int)src[e];
            }
        }
    } else {
        const int* src = (const int*)edges;
        const int* dst = src + N_EDGES;
        for (long long e = idx0; e < N_EDGES; e += stride) {
            if (dst[e] == agent) {
                int p = atomicAdd(&wsi[OFF_MC], 1);
                if (p < MAXM) wsi[OFF_MSRC + p] = src[e];
            }
        }
    }
}

// Pass 2: count dst occurrences (degrees) for the needed node set only.
__global__ void k_count(const void* edges, const int* agent_p, int* wsi) {
    __shared__ int s_nodes[MAXM + 1];
    __shared__ int s_cnt[MAXM + 1];
    __shared__ int s_m;
    int tid = threadIdx.x;
    if (tid == 0) {
        int mc = wsi[OFF_MC];
        s_m = mc < MAXM ? mc : MAXM;
    }
    __syncthreads();
    int m = s_m;
    for (int i = tid; i <= m; i += blockDim.x) {
        s_nodes[i] = (i == 0) ? agent_p[0] : wsi[OFF_MSRC + i - 1];
        s_cnt[i] = 0;
    }
    __syncthreads();
    int i64 = wsi[OFF_FLAG];
    long long idx0 = (long long)blockIdx.x * blockDim.x + threadIdx.x;
    long long stride = (long long)gridDim.x * blockDim.x;
    if (i64) {
        const long long* dst = (const long long*)edges + N_EDGES;
        for (long long e = idx0; e < N_EDGES; e += stride) {
            int d = (int)dst[e];
            for (int j = 0; j <= m; j++)
                if (d == s_nodes[j]) atomicAdd(&s_cnt[j], 1);
        }
    } else {
        const int* dst = (const int*)edges + N_EDGES;
        for (long long e = idx0; e < N_EDGES; e += stride) {
            int d = dst[e];
            for (int j = 0; j <= m; j++)
                if (d == s_nodes[j]) atomicAdd(&s_cnt[j], 1);
        }
    }
    __syncthreads();
    for (int i = tid; i <= m; i += blockDim.x)
        if (s_cnt[i]) atomicAdd(&wsi[OFF_CNT + i], s_cnt[i]);
}

__device__ __forceinline__ float block_sum256(float x, float* red, int tid) {
    #pragma unroll
    for (int o = 32; o > 0; o >>= 1) x += __shfl_down(x, o);
    __syncthreads();
    if ((tid & 63) == 0) red[tid >> 6] = x;
    __syncthreads();
    return red[0] + red[1] + red[2] + red[3];
}

__device__ __forceinline__ void dense_ln_relu(const float* in, const void* w, const void* b,
                                              const void* lnw, const void* lnb, float* out,
                                              float* red, int tid, bool b16) {
    float acc = ldf(b, tid, b16);
    #pragma unroll 8
    for (int k = 0; k < D_HID; k++) acc += in[k] * ldf(w, (long long)k * D_HID + tid, b16);
    float mu = block_sum256(acc, red, tid) * (1.0f / D_HID);
    float d = acc - mu;
    float var = block_sum256(d * d, red, tid) * (1.0f / D_HID);
    float y = d * rsqrtf(var + 1e-5f) * ldf(lnw, tid, b16) + ldf(lnb, tid, b16);
    out[tid] = fmaxf(y, 0.0f);
    __syncthreads();
}

__global__ void __launch_bounds__(256) k_head(
    const void* state, const int* agent_p,
    const void* conv_w, const void* conv_b,
    const void* fc1_w, const void* fc1_b, const void* ln1_w, const void* ln1_b,
    const void* fc2_w, const void* fc2_b, const void* ln2_w, const void* ln2_b,
    const void* mu_w, const void* mu_b,
    const int* wsi, void* out)
{
    __shared__ float xs[D_IN];
    __shared__ float v1[D_HID];
    __shared__ float v2[D_HID];
    __shared__ float red[4];
    int tid = threadIdx.x;
    bool b16 = wsi[OFF_FLAG + 1] != 0;
    int agent = agent_p[0];
    int mc = wsi[OFF_MC];
    int m = mc < MAXM ? mc : MAXM;
    float dinv_a = rsqrtf((float)(wsi[OFF_CNT + 0] + 1));   // deg = count + self loop

    // Weighted sum of input rows (conv is linear): xsum = sum_e w_e * state[src_e]
    if (tid < D_IN) {
        float acc = dinv_a * dinv_a * ldf(state, (long long)agent * D_IN + tid, b16);
        for (int j = 0; j < m; j++) {
            int s = wsi[OFF_MSRC + j];
            float wgt = dinv_a * rsqrtf((float)(wsi[OFF_CNT + 1 + j] + 1));
            acc += wgt * ldf(state, (long long)s * D_IN + tid, b16);
        }
        xs[tid] = acc;
    }
    __syncthreads();

    // conv matvec + bias + relu(row agent)
    {
        float acc = ldf(conv_b, tid, b16);
        #pragma unroll 8
        for (int d = 0; d < D_IN; d++) acc += xs[d] * ldf(conv_w, (long long)d * D_HID + tid, b16);
        v1[tid] = fmaxf(acc, 0.0f);
    }
    __syncthreads();

    dense_ln_relu(v1, fc1_w, fc1_b, ln1_w, ln1_b, v2, red, tid, b16);
    dense_ln_relu(v2, fc2_w, fc2_b, ln2_w, ln2_b, v1, red, tid, b16);

    if (tid < 8) {
        float acc = ldf(mu_b, tid, b16);
        for (int k = 0; k < D_HID; k++) acc += v1[k] * ldf(mu_w, (long long)k * 8 + tid, b16);
        float r = 1.0f / (1.0f + expf(-acc));
        if (b16) ((__hip_bfloat16*)out)[tid] = __float2bfloat16(r);
        else     ((float*)out)[tid] = r;
    }
}

extern "C" void kernel_launch(void* const* d_in, const int* in_sizes, int n_in,
                              void* d_out, int out_size, void* d_ws, size_t ws_size,
                              hipStream_t stream) {
    const void* state = d_in[0];
    const void* edges = d_in[1];
    const int* agent = (const int*)d_in[2];
    int* wsi = (int*)d_ws;

    k_init<<<1, 256, 0, stream>>>(edges, state, wsi);
    k_scan<<<1024, 256, 0, stream>>>(edges, agent, wsi);
    k_count<<<1024, 256, 0, stream>>>(edges, agent, wsi);
    k_head<<<1, 256, 0, stream>>>(state, agent,
                                  d_in[3], d_in[4],
                                  d_in[5], d_in[6], d_in[7], d_in[8],
                                  d_in[9], d_in[10], d_in[11], d_in[12],
                                  d_in[13], d_in[14],
                                  wsi, d_out);
}

// Round 2
// 46.272 us; speedup vs baseline: 1.7636x; 1.7636x over previous
//
#include <hip/hip_runtime.h>
#include <hip/hip_bf16.h>

#define N_NODES 50000
#define N_EDGES 1600000
#define D_IN    128
#define D_HID   256
#define MAXM    2048

// ws layout (in ints):
//  [0] = int64 flag for edge_index, [1] = bf16 flag for float tensors
//  [16] = match_count
//  [32 .. 32+MAXM] = cnt[MAXM+1]   (deg counts: entry 0 = agent, j+1 = match j)
//  [4096 .. 4096+MAXM-1] = match_src[MAXM]
#define OFF_FLAG 0
#define OFF_MC   16
#define OFF_CNT  32
#define OFF_MSRC 4096

__device__ __forceinline__ float ldf(const void* p, long long i, bool b16) {
    if (b16) {
        unsigned short u = ((const unsigned short*)p)[i];
        return __uint_as_float(((unsigned int)u) << 16);
    }
    return ((const float*)p)[i];
}

// paired load of elements i, i+1 (i even)
__device__ __forceinline__ void ld2(const void* p, long long i, bool b16, float& a, float& b) {
    if (b16) {
        unsigned int u = ((const unsigned int*)p)[i >> 1];
        a = __uint_as_float(u << 16);
        b = __uint_as_float(u & 0xffff0000u);
    } else {
        float2 v = ((const float2*)p)[i >> 1];
        a = v.x; b = v.y;
    }
}

__global__ void k_init(const void* edges, const void* state, int* wsi) {
    int tid = threadIdx.x;
    if (tid == 0) {
        const unsigned int* w = (const unsigned int*)edges;
        int i64 = 1;
        for (int k = 1; k < 128; k += 2)
            if (w[k] != 0u) { i64 = 0; break; }
        wsi[OFF_FLAG] = i64;
        const unsigned short* s = (const unsigned short*)state;
        int b16 = 1;
        for (int k = 0; k < 64; k++) {
            unsigned short v = s[k];
            int e = (v >> 7) & 0xff;
            if (!(v == 0 || (e >= 90 && e <= 140))) { b16 = 0; break; }
        }
        wsi[OFF_FLAG + 1] = b16;
        wsi[OFF_MC] = 0;
    }
    for (int i = tid; i < MAXM + 1; i += blockDim.x) wsi[OFF_CNT + i] = 0;
}

__global__ void k_scan(const void* edges, const int* agent_p, int* wsi) {
    int agent = agent_p[0];
    int i64 = wsi[OFF_FLAG];
    long long idx0 = (long long)blockIdx.x * blockDim.x + threadIdx.x;
    long long stride = (long long)gridDim.x * blockDim.x;
    if (i64) {
        const long long* src = (const long long*)edges;
        const long long* dst = src + N_EDGES;
        for (long long e = idx0; e < N_EDGES; e += stride)
            if ((int)dst[e] == agent) {
                int p = atomicAdd(&wsi[OFF_MC], 1);
                if (p < MAXM) wsi[OFF_MSRC + p] = (int)src[e];
            }
    } else {
        const int* src = (const int*)edges;
        const int* dst = src + N_EDGES;
        for (long long e = idx0; e < N_EDGES; e += stride)
            if (dst[e] == agent) {
                int p = atomicAdd(&wsi[OFF_MC], 1);
                if (p < MAXM) wsi[OFF_MSRC + p] = src[e];
            }
    }
}

__global__ void k_count(const void* edges, const int* agent_p, int* wsi) {
    __shared__ int s_nodes[MAXM + 1];
    __shared__ int s_cnt[MAXM + 1];
    __shared__ int s_m;
    int tid = threadIdx.x;
    if (tid == 0) {
        int mc = wsi[OFF_MC];
        s_m = mc < MAXM ? mc : MAXM;
    }
    __syncthreads();
    int m = s_m;
    for (int i = tid; i <= m; i += blockDim.x) {
        s_nodes[i] = (i == 0) ? agent_p[0] : wsi[OFF_MSRC + i - 1];
        s_cnt[i] = 0;
    }
    __syncthreads();
    int i64 = wsi[OFF_FLAG];
    long long idx0 = (long long)blockIdx.x * blockDim.x + threadIdx.x;
    long long stride = (long long)gridDim.x * blockDim.x;
    if (i64) {
        const long long* dst = (const long long*)edges + N_EDGES;
        for (long long e = idx0; e < N_EDGES; e += stride) {
            int d = (int)dst[e];
            for (int j = 0; j <= m; j++)
                if (d == s_nodes[j]) atomicAdd(&s_cnt[j], 1);
        }
    } else {
        const int* dst = (const int*)edges + N_EDGES;
        for (long long e = idx0; e < N_EDGES; e += stride) {
            int d = dst[e];
            for (int j = 0; j <= m; j++)
                if (d == s_nodes[j]) atomicAdd(&s_cnt[j], 1);
        }
    }
    __syncthreads();
    for (int i = tid; i <= m; i += blockDim.x)
        if (s_cnt[i]) atomicAdd(&wsi[OFF_CNT + i], s_cnt[i]);
}

__device__ __forceinline__ float sum256b(const float* buf, int tid, float* s_scal) {
    __syncthreads();
    if (tid < 64) {
        float x = buf[tid] + buf[tid + 64] + buf[tid + 128] + buf[tid + 192];
        #pragma unroll
        for (int o = 32; o > 0; o >>= 1) x += __shfl_down(x, o);
        if (tid == 0) *s_scal = x;
    }
    __syncthreads();
    return *s_scal;
}

__global__ void __launch_bounds__(1024) k_head(
    const void* state, const int* agent_p,
    const void* conv_w, const void* conv_b,
    const void* fc1_w, const void* fc1_b, const void* ln1_w, const void* ln1_b,
    const void* fc2_w, const void* fc2_b, const void* ln2_w, const void* ln2_b,
    const void* mu_w, const void* mu_b,
    const int* wsi, void* out)
{
    __shared__ float s_wgt[MAXM];
    __shared__ int   s_srcl[MAXM];
    __shared__ float scratch[2048];   // K-split partials / LN buffer
    __shared__ float xs[D_IN];
    __shared__ float v1[D_HID];
    __shared__ float v2[D_HID];
    __shared__ float s_scal;

    int tid = threadIdx.x;
    bool b16 = wsi[OFF_FLAG + 1] != 0;
    int agent = agent_p[0];
    int mc = wsi[OFF_MC];
    int m = mc < MAXM ? mc : MAXM;
    float dinv_a = rsqrtf((float)(wsi[OFF_CNT + 0] + 1));

    // Phase 0: stage edge srcs + norm weights into LDS (parallel)
    for (int i = tid; i < m; i += 1024) {
        s_srcl[i] = wsi[OFF_MSRC + i];
        s_wgt[i]  = dinv_a * rsqrtf((float)(wsi[OFF_CNT + 1 + i] + 1));
    }
    __syncthreads();

    // Phase 1: xsum[128] = dinv_a^2*state[agent] + sum_j wgt[j]*state[src_j]
    // 16 j-groups x 64 d-pairs
    {
        int jg = tid >> 6;            // 0..15
        int d2 = (tid & 63) * 2;      // even element
        float a0 = 0.0f, a1 = 0.0f;
        if (jg == 0) {
            float sa, sb;
            ld2(state, (long long)agent * D_IN + d2, b16, sa, sb);
            a0 = dinv_a * dinv_a * sa;
            a1 = dinv_a * dinv_a * sb;
        }
        for (int j = jg; j < m; j += 16) {
            int s = s_srcl[j];
            float w = s_wgt[j];
            float sa, sb;
            ld2(state, (long long)s * D_IN + d2, b16, sa, sb);
            a0 += w * sa;
            a1 += w * sb;
        }
        scratch[jg * 128 + d2]     = a0;
        scratch[jg * 128 + d2 + 1] = a1;
    }
    __syncthreads();
    if (tid < D_IN) {
        float acc = 0.0f;
        #pragma unroll
        for (int g = 0; g < 16; g++) acc += scratch[g * 128 + tid];
        xs[tid] = acc;
    }
    __syncthreads();

    // Phase 2: conv matvec 128->256, 8 K-slices of 16, paired outputs
    {
        int og = tid & 127;           // output pair index
        int ks = tid >> 7;            // 0..7
        int o2 = og * 2;
        float a0 = 0.0f, a1 = 0.0f;
        int kbeg = ks * 16;
        #pragma unroll 8
        for (int k = kbeg; k < kbeg + 16; k++) {
            float xv = xs[k];
            float w0, w1;
            ld2(conv_w, (long long)k * D_HID + o2, b16, w0, w1);
            a0 += xv * w0;
            a1 += xv * w1;
        }
        scratch[ks * 256 + o2]     = a0;
        scratch[ks * 256 + o2 + 1] = a1;
    }
    __syncthreads();
    if (tid < D_HID) {
        float h = ldf(conv_b, tid, b16);
        #pragma unroll
        for (int s = 0; s < 8; s++) h += scratch[s * 256 + tid];
        v1[tid] = fmaxf(h, 0.0f);
    }
    __syncthreads();

    // Phase 3 & 4: fc layers 256->256 with LN+relu
    const void* fw[2]  = { fc1_w, fc2_w };
    const void* fb[2]  = { fc1_b, fc2_b };
    const void* lw[2]  = { ln1_w, ln2_w };
    const void* lb[2]  = { ln1_b, ln2_b };
    float* vin  = v1;
    float* vout = v2;
    for (int L = 0; L < 2; L++) {
        {
            int og = tid & 127;
            int ks = tid >> 7;        // 0..7
            int o2 = og * 2;
            float a0 = 0.0f, a1 = 0.0f;
            int kbeg = ks * 32;
            #pragma unroll 8
            for (int k = kbeg; k < kbeg + 32; k++) {
                float xv = vin[k];
                float w0, w1;
                ld2(fw[L], (long long)k * D_HID + o2, b16, w0, w1);
                a0 += xv * w0;
                a1 += xv * w1;
            }
            scratch[ks * 256 + o2]     = a0;
            scratch[ks * 256 + o2 + 1] = a1;
        }
        __syncthreads();
        float h = 0.0f;
        if (tid < D_HID) {
            h = ldf(fb[L], tid, b16);
            #pragma unroll
            for (int s = 0; s < 8; s++) h += scratch[s * 256 + tid];
            scratch[tid] = h;         // column tid only touched by thread tid
        }
        float mu = sum256b(scratch, tid, &s_scal) * (1.0f / D_HID);
        float d = h - mu;
        if (tid < D_HID) scratch[tid] = d * d;
        float var = sum256b(scratch, tid, &s_scal) * (1.0f / D_HID);
        if (tid < D_HID) {
            float y = d * rsqrtf(var + 1e-5f) * ldf(lw[L], tid, b16) + ldf(lb[L], tid, b16);
            vout[tid] = fmaxf(y, 0.0f);
        }
        __syncthreads();
        float* t = vin; vin = vout; vout = t;
    }

    // Phase 5: mu head 256->8, sigmoid. vin holds final hidden.
    if (tid < 64) {
        int o = tid & 7;
        int ks = tid >> 3;            // 0..7
        float acc = 0.0f;
        int kbeg = ks * 32;
        #pragma unroll 8
        for (int k = kbeg; k < kbeg + 32; k++)
            acc += vin[k] * ldf(mu_w, (long long)k * 8 + o, b16);
        scratch[ks * 8 + o] = acc;
    }
    __syncthreads();
    if (tid < 8) {
        float acc = ldf(mu_b, tid, b16);
        #pragma unroll
        for (int s = 0; s < 8; s++) acc += scratch[s * 8 + tid];
        float r = 1.0f / (1.0f + expf(-acc));
        if (b16) ((__hip_bfloat16*)out)[tid] = __float2bfloat16(r);
        else     ((float*)out)[tid] = r;
    }
}

extern "C" void kernel_launch(void* const* d_in, const int* in_sizes, int n_in,
                              void* d_out, int out_size, void* d_ws, size_t ws_size,
                              hipStream_t stream) {
    const void* state = d_in[0];
    const void* edges = d_in[1];
    const int* agent = (const int*)d_in[2];
    int* wsi = (int*)d_ws;

    k_init<<<1, 256, 0, stream>>>(edges, state, wsi);
    k_scan<<<1024, 256, 0, stream>>>(edges, agent, wsi);
    k_count<<<1024, 256, 0, stream>>>(edges, agent, wsi);
    k_head<<<1, 1024, 0, stream>>>(state, agent,
                                   d_in[3], d_in[4],
                                   d_in[5], d_in[6], d_in[7], d_in[8],
                                   d_in[9], d_in[10], d_in[11], d_in[12],
                                   d_in[13], d_in[14],
                                   wsi, d_out);
}

// Round 3
// 44.725 us; speedup vs baseline: 1.8246x; 1.0346x over previous
//
#include <hip/hip_runtime.h>
#include <hip/hip_bf16.h>

#define N_EDGES 1600000
#define D_IN    128
#define D_HID   256
#define MAXM    2048

// ws int layout:
//  [0]=i64 flag, [1]=bf16 flag, [16]=match_count
//  [32..32+MAXM]   cnt (deg counts: 0=agent, 1+j=match j)
//  [4096..6143]    match src list
//  float regions (same 4B indexing): [8192..8447]=h0, [8704..8959]=h1raw, [9216..9471]=h2raw
#define OFF_FLAG 0
#define OFF_MC   16
#define OFF_CNT  32
#define OFF_MSRC 4096
#define OFF_H0   8192
#define OFF_H1   8704
#define OFF_H2   9216

__device__ __forceinline__ float ldf(const void* p, long long i, bool b16) {
    if (b16) {
        unsigned short u = ((const unsigned short*)p)[i];
        return __uint_as_float(((unsigned int)u) << 16);
    }
    return ((const float*)p)[i];
}

__global__ void __launch_bounds__(256) k_init(const void* edges, const void* state, int* wsi) {
    int tid = threadIdx.x;
    if (tid < 64) {
        // int64 detection: odd 32-bit words of first 64 values all zero -> int64
        const unsigned int* w = (const unsigned int*)edges;
        unsigned long long b = __ballot(w[2 * tid + 1] == 0u);
        if (tid == 0) wsi[OFF_FLAG] = (b == 0xFFFFFFFFFFFFFFFFULL) ? 1 : 0;
    } else if (tid < 128) {
        // bf16 detection on state ~ N(0,1): every 16-bit word plausible as bf16
        const unsigned short* s = (const unsigned short*)state;
        unsigned short v = s[tid - 64];
        int e = (v >> 7) & 0xff;
        unsigned long long b = __ballot(v == 0 || (e >= 90 && e <= 140));
        if (tid == 64) wsi[OFF_FLAG + 1] = (b == 0xFFFFFFFFFFFFFFFFULL) ? 1 : 0;
    }
    if (tid == 128) wsi[OFF_MC] = 0;
    for (int i = tid; i < MAXM + 1; i += 256) wsi[OFF_CNT + i] = 0;
}

__global__ void __launch_bounds__(256) k_scan(const void* edges, const int* agent_p, int* wsi) {
    int agent = agent_p[0];
    int i64 = wsi[OFF_FLAG];
    long long idx0 = (long long)blockIdx.x * blockDim.x + threadIdx.x;
    long long stride = (long long)gridDim.x * blockDim.x;
    if (i64) {
        const long long* src = (const long long*)edges;
        const long long* dst = src + N_EDGES;
        for (long long e = idx0; e < N_EDGES; e += stride)
            if ((int)dst[e] == agent) {
                int p = atomicAdd(&wsi[OFF_MC], 1);
                if (p < MAXM) wsi[OFF_MSRC + p] = (int)src[e];
            }
    } else {
        const int* src = (const int*)edges;
        const int* dst = src + N_EDGES;
        for (long long e = idx0; e < N_EDGES; e += stride)
            if (dst[e] == agent) {
                int p = atomicAdd(&wsi[OFF_MC], 1);
                if (p < MAXM) wsi[OFF_MSRC + p] = src[e];
            }
    }
}

__global__ void __launch_bounds__(256) k_count(const void* edges, const int* agent_p, int* wsi) {
    __shared__ int s_nodes[MAXM + 1];
    __shared__ int s_cnt[MAXM + 1];
    __shared__ int s_m;
    int tid = threadIdx.x;
    if (tid == 0) {
        int mc = wsi[OFF_MC];
        s_m = mc < MAXM ? mc : MAXM;
    }
    __syncthreads();
    int m = s_m;
    for (int i = tid; i <= m; i += blockDim.x) {
        s_nodes[i] = (i == 0) ? agent_p[0] : wsi[OFF_MSRC + i - 1];
        s_cnt[i] = 0;
    }
    __syncthreads();
    int i64 = wsi[OFF_FLAG];
    long long idx0 = (long long)blockIdx.x * blockDim.x + threadIdx.x;
    long long stride = (long long)gridDim.x * blockDim.x;
    if (i64) {
        const long long* dst = (const long long*)edges + N_EDGES;
        for (long long e = idx0; e < N_EDGES; e += stride) {
            int d = (int)dst[e];
            for (int j = 0; j <= m; j++)
                if (d == s_nodes[j]) atomicAdd(&s_cnt[j], 1);
        }
    } else {
        const int* dst = (const int*)edges + N_EDGES;
        for (long long e = idx0; e < N_EDGES; e += stride) {
            int d = dst[e];
            for (int j = 0; j <= m; j++)
                if (d == s_nodes[j]) atomicAdd(&s_cnt[j], 1);
        }
    }
    __syncthreads();
    for (int i = tid; i <= m; i += blockDim.x)
        if (s_cnt[i]) atomicAdd(&wsi[OFF_CNT + i], s_cnt[i]);
}

// conv: 8 blocks x 32 outputs. Each block redundantly gathers xs[128] then does its slice.
__global__ void __launch_bounds__(256) k_conv(const void* state, const int* agent_p,
                                              const void* conv_w, const void* conv_b,
                                              const int* wsi, float* wsf) {
    __shared__ int   s_src[MAXM];
    __shared__ float s_w[MAXM];
    __shared__ float s_part[256];
    __shared__ float s_xs[D_IN];
    int tid = threadIdx.x;
    bool b16 = wsi[OFF_FLAG + 1] != 0;
    int agent = agent_p[0];
    int mc = wsi[OFF_MC];
    int m = mc < MAXM ? mc : MAXM;
    float dinv_a = rsqrtf((float)(wsi[OFF_CNT] + 1));
    for (int i = tid; i < m; i += 256) {
        s_src[i] = wsi[OFF_MSRC + i];
        s_w[i]   = dinv_a * rsqrtf((float)(wsi[OFF_CNT + 1 + i] + 1));
    }
    __syncthreads();
    // gather: (jg, d) split; 2 j-groups x 128 dims
    int d = tid & 127, jg = tid >> 7;
    float acc = (jg == 0) ? dinv_a * dinv_a * ldf(state, (long long)agent * D_IN + d, b16) : 0.0f;
    for (int j = jg; j < m; j += 2)
        acc += s_w[j] * ldf(state, (long long)s_src[j] * D_IN + d, b16);
    s_part[tid] = acc;
    __syncthreads();
    if (tid < D_IN) s_xs[tid] = s_part[tid] + s_part[tid + 128];
    __syncthreads();
    // matvec slice: o = blk*32 + (tid&31), 8 K-slices of 16
    int o = blockIdx.x * 32 + (tid & 31);
    int ks = tid >> 5;
    float a = 0.0f;
    #pragma unroll 4
    for (int k = ks * 16; k < ks * 16 + 16; k++)
        a += s_xs[k] * ldf(conv_w, (long long)k * D_HID + o, b16);
    s_part[tid] = a;
    __syncthreads();
    if (tid < 32) {
        int oo = blockIdx.x * 32 + tid;
        float h = ldf(conv_b, oo, b16);
        #pragma unroll
        for (int s = 0; s < 8; s++) h += s_part[s * 32 + tid];
        wsf[OFF_H0 + oo] = fmaxf(h, 0.0f);
    }
}

// fc layer: 8 blocks x 32 outputs. Optionally applies LN(prev)+relu redundantly per block.
// Writes RAW (pre-LN) output; consumer applies its LN.
__global__ void __launch_bounds__(256) k_fc(const void* w, const void* b,
                                            const void* lnw, const void* lnb, int do_ln,
                                            const int* wsi, float* wsf, int in_off, int out_off) {
    __shared__ float s_in[D_HID];
    __shared__ float s_part[256];
    __shared__ float s_red[8];
    int tid = threadIdx.x;
    bool b16 = wsi[OFF_FLAG + 1] != 0;
    float v = wsf[in_off + tid];
    if (do_ln) {
        float s1 = v;
        #pragma unroll
        for (int o = 32; o > 0; o >>= 1) s1 += __shfl_down(s1, o);
        if ((tid & 63) == 0) s_red[tid >> 6] = s1;
        __syncthreads();
        float mu = (s_red[0] + s_red[1] + s_red[2] + s_red[3]) * (1.0f / D_HID);
        float dd = v - mu;
        float s2 = dd * dd;
        #pragma unroll
        for (int o = 32; o > 0; o >>= 1) s2 += __shfl_down(s2, o);
        if ((tid & 63) == 0) s_red[4 + (tid >> 6)] = s2;
        __syncthreads();
        float var = (s_red[4] + s_red[5] + s_red[6] + s_red[7]) * (1.0f / D_HID);
        v = fmaxf(dd * rsqrtf(var + 1e-5f) * ldf(lnw, tid, b16) + ldf(lnb, tid, b16), 0.0f);
    }
    s_in[tid] = v;
    __syncthreads();
    int o = blockIdx.x * 32 + (tid & 31);
    int ks = tid >> 5;
    float a = 0.0f;
    #pragma unroll 8
    for (int k = ks * 32; k < ks * 32 + 32; k++)
        a += s_in[k] * ldf(w, (long long)k * D_HID + o, b16);
    s_part[tid] = a;
    __syncthreads();
    if (tid < 32) {
        int oo = blockIdx.x * 32 + tid;
        float h = ldf(b, oo, b16);
        #pragma unroll
        for (int s = 0; s < 8; s++) h += s_part[s * 32 + tid];
        wsf[out_off + oo] = h;
    }
}

// final head: 1 block. LN(ln2)+relu on h2raw, 256x8 matvec, sigmoid, store.
__global__ void __launch_bounds__(256) k_mu(const void* muw, const void* mub,
                                            const void* lnw, const void* lnb,
                                            const int* wsi, float* wsf, void* out) {
    __shared__ float s_in[D_HID];
    __shared__ float s_part[256];
    __shared__ float s_red[8];
    int tid = threadIdx.x;
    bool b16 = wsi[OFF_FLAG + 1] != 0;
    float v = wsf[OFF_H2 + tid];
    {
        float s1 = v;
        #pragma unroll
        for (int o = 32; o > 0; o >>= 1) s1 += __shfl_down(s1, o);
        if ((tid & 63) == 0) s_red[tid >> 6] = s1;
        __syncthreads();
        float mu = (s_red[0] + s_red[1] + s_red[2] + s_red[3]) * (1.0f / D_HID);
        float dd = v - mu;
        float s2 = dd * dd;
        #pragma unroll
        for (int o = 32; o > 0; o >>= 1) s2 += __shfl_down(s2, o);
        if ((tid & 63) == 0) s_red[4 + (tid >> 6)] = s2;
        __syncthreads();
        float var = (s_red[4] + s_red[5] + s_red[6] + s_red[7]) * (1.0f / D_HID);
        v = fmaxf(dd * rsqrtf(var + 1e-5f) * ldf(lnw, tid, b16) + ldf(lnb, tid, b16), 0.0f);
    }
    s_in[tid] = v;
    __syncthreads();
    int o = tid & 7, ks = tid >> 3;   // 32 K-slices of 8
    float a = 0.0f;
    #pragma unroll 8
    for (int k = ks * 8; k < ks * 8 + 8; k++)
        a += s_in[k] * ldf(muw, (long long)k * 8 + o, b16);
    s_part[tid] = a;
    __syncthreads();
    if (tid < 8) {
        float acc = ldf(mub, tid, b16);
        #pragma unroll
        for (int s = 0; s < 32; s++) acc += s_part[s * 8 + tid];
        float r = 1.0f / (1.0f + expf(-acc));
        if (b16) ((__hip_bfloat16*)out)[tid] = __float2bfloat16(r);
        else     ((float*)out)[tid] = r;
    }
}

extern "C" void kernel_launch(void* const* d_in, const int* in_sizes, int n_in,
                              void* d_out, int out_size, void* d_ws, size_t ws_size,
                              hipStream_t stream) {
    const void* state = d_in[0];
    const void* edges = d_in[1];
    const int* agent = (const int*)d_in[2];
    int* wsi = (int*)d_ws;
    float* wsf = (float*)d_ws;

    k_init<<<1, 256, 0, stream>>>(edges, state, wsi);
    k_scan<<<1024, 256, 0, stream>>>(edges, agent, wsi);
    k_count<<<1024, 256, 0, stream>>>(edges, agent, wsi);
    k_conv<<<8, 256, 0, stream>>>(state, agent, d_in[3], d_in[4], wsi, wsf);
    k_fc<<<8, 256, 0, stream>>>(d_in[5], d_in[6], nullptr, nullptr, 0, wsi, wsf, OFF_H0, OFF_H1);
    k_fc<<<8, 256, 0, stream>>>(d_in[9], d_in[10], d_in[7], d_in[8], 1, wsi, wsf, OFF_H1, OFF_H2);
    k_mu<<<1, 256, 0, stream>>>(d_in[13], d_in[14], d_in[11], d_in[12], wsi, wsf, d_out);
}